// Round 1
// baseline (259.660 us; speedup 1.0000x reference)
//
#include <hip/hip_runtime.h>
#include <math.h>

// ---- NSA hyperparameters (compile-time, matches reference config) ----
constexpr int kT    = 2048;
constexpr int kHQ   = 16;
constexpr int kD    = 128;
constexpr int kKS   = 32;
constexpr int kST   = 16;
constexpr int kBS   = 64;
constexpr int kM    = (kT - kKS) / kST + 1;   // 127 compressed tokens
constexpr int kNB   = (kT + kBS - 1) / kBS;   // 32 selection blocks
constexpr int kTopN = 16;
constexpr int kNInit = 2;
constexpr int kWIN  = 512;
constexpr float kNEG = -1e30f;
constexpr float kScale = 0.08838834764831845f; // 128^-0.5

constexpr int kPad    = 32;
constexpr int kKBRows = kT + kPad; // 2080
constexpr int kVTCols = kT + kPad; // 2080

// K2 (cmp-attn) LDS strides
constexpr int kQS2 = kD + 4;   // 132 floats
constexpr int kPS2 = 132;      // fp32 probs
constexpr int kPB2 = 136;      // bf16 probs

// K4 tiled attention (kQT=4: 4 waves, 4 queries, grid=512)
constexpr int kQT   = 4;
constexpr int kPSt  = 72;         // P row stride (fp16)

typedef __attribute__((ext_vector_type(8))) short short8;
typedef __attribute__((ext_vector_type(8))) _Float16 half8;
typedef __attribute__((ext_vector_type(2))) _Float16 half2v;
typedef __attribute__((ext_vector_type(4))) float floatx4;

// RNE float -> bf16 bits
__device__ inline short f2bf(float x) {
    unsigned u = __float_as_uint(x);
    unsigned r = (u + 0x7fffu + ((u >> 16) & 1u)) >> 16;
    return (short)r;
}

// ---------------------------------------------------------------------
// K1: fused staging.  blocks [0,2080): bf16 K rows + fp16 V^T cols,
// V^T stored with per-64-block key permutation col = 2l + (kt&1) + 32(kt>>1)
// (key = 16kt + l) so K4's P-writes pack as b32 pairs.
// blocks [2080,2208): mean-pool cmp_k fp32 + cmp V^T bf16.  block=(128)
// ---------------------------------------------------------------------
__global__ void k_stage(const float* __restrict__ k, const float* __restrict__ v,
                        short* __restrict__ kb, _Float16* __restrict__ vt,
                        float* __restrict__ cmp_k, short* __restrict__ cvt) {
    const int bid = blockIdx.x;
    const int d = threadIdx.x;
    if (bid < kKBRows) {
        const int row = bid;
        const int blk = row >> 6, w = row & 63;
        const int kt = w >> 4, l = w & 15;
        const int col = blk * kBS + l * 2 + (kt & 1) + (kt >> 1) * 32;
        if (row < kT) {
            kb[row * kD + d] = f2bf(k[(size_t)row * kD + d]);
            vt[(size_t)d * kVTCols + col] = (_Float16)v[(size_t)row * kD + d];
        } else {
            kb[row * kD + d] = 0;
            vt[(size_t)d * kVTCols + col] = (_Float16)0.f;
        }
    } else {
        const int m = bid - kKBRows;        // 0..127 (127 = zero pad row)
        float sk = 0.f, sv = 0.f;
        if (m < kM) {
            const int base = m * kST;
            #pragma unroll
            for (int i = 0; i < kKS; ++i) {
                sk += k[(size_t)(base + i) * kD + d];
                sv += v[(size_t)(base + i) * kD + d];
            }
            sk *= (1.0f / kKS);
            sv *= (1.0f / kKS);
        }
        cmp_k[m * kD + d] = sk;
        cvt[d * 128 + m] = f2bf(sv);
    }
}

// ---------------------------------------------------------------------
// K2: compressed attention + fused top-k, all 16 heads of one t.
// QK + softmax + slc_p + topk: fp32, arithmetic identical to prior
// passing versions (selection-sensitive).  PV: bf16 MFMA.
// grid=(T), block=(256)
// ---------------------------------------------------------------------
__global__ __launch_bounds__(256) void k_cmp_attn(
        const float* __restrict__ q, const float* __restrict__ cw,
        const float* __restrict__ cmp_k, const short* __restrict__ cvt,
        unsigned* __restrict__ sel_mask, float* __restrict__ out) {
    const int t = blockIdx.x;
    const int tid = threadIdx.x;
    const int wave = tid >> 6;
    const int lane = tid & 63;
    const int l15 = lane & 15;
    const int quad = lane >> 4;

    __shared__ float q_s[kHQ * kQS2];
    __shared__ float p_s[kHQ * kPS2];
    __shared__ short Pb[kHQ * kPB2];
    __shared__ float sp[kNB];

    for (int i = tid; i < kHQ * kD; i += 256) {
        int h = i >> 7, d = i & 127;
        q_s[h * kQS2 + d] = q[(size_t)t * kHQ * kD + i];
    }
    __syncthreads();

    const int nvalid = (t >= kKS - 1) ? min(kM, (t - (kKS - 1)) / kST + 1) : 0;

    for (int idx = tid; idx < nvalid * 4; idx += 256) {
        const int m = idx >> 2;
        const int h0 = (idx & 3) * 4;
        const float4* k4 = (const float4*)(cmp_k + (size_t)m * kD);
        float a0 = 0.f, a1 = 0.f, a2 = 0.f, a3 = 0.f;
        #pragma unroll
        for (int i = 0; i < kD / 4; ++i) {
            const float4 b = k4[i];
            const float4 qa = *(const float4*)&q_s[(h0 + 0) * kQS2 + i * 4];
            const float4 qb = *(const float4*)&q_s[(h0 + 1) * kQS2 + i * 4];
            const float4 qc = *(const float4*)&q_s[(h0 + 2) * kQS2 + i * 4];
            const float4 qd = *(const float4*)&q_s[(h0 + 3) * kQS2 + i * 4];
            a0 = fmaf(qa.x, b.x, fmaf(qa.y, b.y, fmaf(qa.z, b.z, fmaf(qa.w, b.w, a0))));
            a1 = fmaf(qb.x, b.x, fmaf(qb.y, b.y, fmaf(qb.z, b.z, fmaf(qb.w, b.w, a1))));
            a2 = fmaf(qc.x, b.x, fmaf(qc.y, b.y, fmaf(qc.z, b.z, fmaf(qc.w, b.w, a2))));
            a3 = fmaf(qd.x, b.x, fmaf(qd.y, b.y, fmaf(qd.z, b.z, fmaf(qd.w, b.w, a3))));
        }
        p_s[(h0 + 0) * kPS2 + m] = a0 * kScale;
        p_s[(h0 + 1) * kPS2 + m] = a1 * kScale;
        p_s[(h0 + 2) * kPS2 + m] = a2 * kScale;
        p_s[(h0 + 3) * kPS2 + m] = a3 * kScale;
    }
    __syncthreads();

    if (tid < kHQ) {
        float* p = p_s + tid * kPS2;
        short* pb = Pb + tid * kPB2;
        if (nvalid == 0) {
            for (int m = 0; m < 128; ++m) { p[m] = 0.f; pb[m] = 0; }
        } else {
            float mx = kNEG;
            for (int m = 0; m < nvalid; ++m) mx = fmaxf(mx, p[m]);
            float l = 0.f;
            for (int m = 0; m < nvalid; ++m) { float e = __expf(p[m] - mx); p[m] = e; l += e; }
            float inv = 1.f / l;
            for (int m = 0; m < nvalid; ++m) { float pn = p[m] * inv; p[m] = pn; pb[m] = f2bf(pn); }
            for (int m = nvalid; m < 128; ++m) { p[m] = 0.f; pb[m] = 0; }
        }
    }
    __syncthreads();

    if (tid < kNB) {
        const int b = tid;
        const int m0 = 4 * b;
        float acc = 0.f;
        for (int h = 0; h < kHQ; ++h) {
            const float* p = p_s + h * kPS2;
            float a = 0.f;
            a += p[m0];
            a += p[m0 + 1];
            a += p[m0 + 2];
            a += 0.5f * p[m0 + 3];
            if (m0 - 1 >= 0) a += 0.5f * p[m0 - 1];
            acc += a;
        }
        sp[b] = acc;
    }
    __syncthreads();

    // ---- fused top-k (identical semantics to reference ordering) ----
    if (tid == 0) {
        const int cur = t / kBS;
        float vals[kNB];
        #pragma unroll
        for (int b = 0; b < kNB; ++b) {
            float x = sp[b];
            if (b > cur) x = kNEG;
            if (b < kNInit || b == cur) x = 1e30f;
            vals[b] = x;
        }
        unsigned mask = 0;
        for (int n = 0; n < kTopN; ++n) {
            float best = -3.0e38f; int bi = 0;
            #pragma unroll
            for (int b = 0; b < kNB; ++b) {
                bool taken = (mask >> b) & 1u;
                if (!taken && vals[b] > best) { best = vals[b]; bi = b; }
            }
            mask |= (1u << bi);
        }
        sel_mask[t] = mask;
    }

    const int dimbase = wave * 32;
    floatx4 o[2] = {{0,0,0,0},{0,0,0,0}};
    #pragma unroll
    for (int kc = 0; kc < 4; ++kc) {
        const short8 ap = *(const short8*)&Pb[l15 * kPB2 + kc * 32 + quad * 8];
        #pragma unroll
        for (int nt = 0; nt < 2; ++nt) {
            const short8 b = *(const short8*)(cvt + (size_t)(dimbase + nt * 16 + l15) * 128 + kc * 32 + quad * 8);
            o[nt] = __builtin_amdgcn_mfma_f32_16x16x32_bf16(ap, b, o[nt], 0, 0, 0);
        }
    }

    #pragma unroll
    for (int r = 0; r < 4; ++r) {
        const int head = quad * 4 + r;
        const float c0 = cw[((size_t)t * kHQ + head) * 3 + 0];
        const float w0 = 1.f / (1.f + __expf(-c0));
        #pragma unroll
        for (int nt = 0; nt < 2; ++nt)
            out[((size_t)t * kHQ + head) * kD + dimbase + nt * 16 + l15] = w0 * o[nt][r];
    }
}

// ---------------------------------------------------------------------
// K4: barrier-free select+SWA attention.  One WAVE = one query t, all
// 128 output dims; 4 waves per block (grid=T/4) but waves never sync
// after launch.  Per block b in the wave's own (sel|window) list:
//   - K B-frags direct from global kb (L2-resident, MFMA layout)
//   - QK bf16 MFMA -> per-head online softmax (per-path skip)
//   - P staged through a per-wave-private LDS slab (in-wave lgkmcnt
//     ordering only, no s_barrier) with the permuted b32 packing that
//     matches vt's key permutation
//   - PV f16 MFMA over all 8 dim-tiles, V B-frags direct from vt (L2)
// ---------------------------------------------------------------------
__global__ __launch_bounds__(256, 2) void k_attn_tile(
        const float* __restrict__ q, const short* __restrict__ kb,
        const _Float16* __restrict__ vt, const float* __restrict__ cw,
        const unsigned* __restrict__ sel_mask, float* __restrict__ out) {
    const int tid = threadIdx.x;
    const int wave = tid >> 6;
    const int lane = tid & 63;
    const int l15 = lane & 15;
    const int quad = lane >> 4;
    const int t_w = blockIdx.x * kQT + wave;

    // per-wave private P slabs: [wave][path][16 rows x kPSt fp16]
    __shared__ _Float16 Pw[kQT][2][16 * kPSt];   // 18.4 KB total
    _Float16* const PS = &Pw[wave][0][0];
    _Float16* const PW = &Pw[wave][1][0];

    // A-fragments: q[t_w][head=l15][.] * kScale -> bf16
    short8 aq[4];
    {
        const float* qp = q + ((size_t)t_w * kHQ + l15) * kD + quad * 8;
        #pragma unroll
        for (int c = 0; c < 4; ++c) {
            const float4 f0 = *(const float4*)(qp + c * 32);
            const float4 f1 = *(const float4*)(qp + c * 32 + 4);
            short8 a;
            a[0] = f2bf(f0.x * kScale); a[1] = f2bf(f0.y * kScale);
            a[2] = f2bf(f0.z * kScale); a[3] = f2bf(f0.w * kScale);
            a[4] = f2bf(f1.x * kScale); a[5] = f2bf(f1.y * kScale);
            a[6] = f2bf(f1.z * kScale); a[7] = f2bf(f1.w * kScale);
            aq[c] = a;
        }
    }

    const unsigned selm = sel_mask[t_w];
    const int cur = t_w >> 6;
    const int lob = max(0, (t_w - (kWIN - 1)) >> 6);   // lowest block with any windowed key

    float msel[4], lsel[4], mswa[4], lswa[4];
    #pragma unroll
    for (int r = 0; r < 4; ++r) { msel[r] = kNEG; lsel[r] = 0.f; mswa[r] = kNEG; lswa[r] = 0.f; }
    floatx4 osel[8], oswa[8];
    #pragma unroll
    for (int n8 = 0; n8 < 8; ++n8) {
        osel[n8] = (floatx4){0,0,0,0};
        oswa[n8] = (floatx4){0,0,0,0};
    }

    for (int b = 0; b <= cur; ++b) {
        const bool bsel = (selm >> b) & 1u;
        const bool bswa = b >= lob;
        if (!(bsel | bswa)) continue;

        // ---- QK: K B-frags straight from global (L2-resident) ----
        floatx4 acc[4];
        #pragma unroll
        for (int kt = 0; kt < 4; ++kt) {
            acc[kt] = (floatx4){0,0,0,0};
            const short* kp = kb + (size_t)(b * kBS + kt * 16 + l15) * kD + quad * 8;
            #pragma unroll
            for (int c = 0; c < 4; ++c) {
                const short8 bf = *(const short8*)(kp + c * 32);
                acc[kt] = __builtin_amdgcn_mfma_f32_16x16x32_bf16(aq[c], bf, acc[kt], 0, 0, 0);
            }
        }

        bool ca[4], wi[4];
        #pragma unroll
        for (int kt = 0; kt < 4; ++kt) {
            const int key = b * kBS + kt * 16 + l15;
            ca[kt] = key <= t_w;
            wi[kt] = ca[kt] && (t_w - key) < kWIN;
        }

        // ---- online softmax (per-path, shared-exp when both active) ----
        float axs[4], axw[4];
        if (bsel && bswa) {
            #pragma unroll
            for (int r = 0; r < 4; ++r) {
                float mxs = kNEG, mxw = kNEG;
                #pragma unroll
                for (int kt = 0; kt < 4; ++kt) {
                    const float s = acc[kt][r];
                    if (ca[kt]) mxs = fmaxf(mxs, s);
                    if (wi[kt]) mxw = fmaxf(mxw, s);
                }
                #pragma unroll
                for (int off = 8; off; off >>= 1) {
                    mxs = fmaxf(mxs, __shfl_xor(mxs, off, 16));
                    mxw = fmaxf(mxw, __shfl_xor(mxw, off, 16));
                }
                const float msn = fmaxf(msel[r], mxs);
                const float mwn = fmaxf(mswa[r], mxw);
                axs[r] = __expf(msel[r] - msn);
                axw[r] = __expf(mswa[r] - mwn);
                const float cr = __expf(msn - mwn);
                float es[4], ew[4];
                #pragma unroll
                for (int kt = 0; kt < 4; ++kt) {
                    const float e0 = ca[kt] ? __expf(acc[kt][r] - msn) : 0.f;
                    es[kt] = e0;
                    ew[kt] = wi[kt] ? e0 * cr : 0.f;
                }
                float sums = (es[0] + es[1]) + (es[2] + es[3]);
                float sumw = (ew[0] + ew[1]) + (ew[2] + ew[3]);
                #pragma unroll
                for (int off = 8; off; off >>= 1) {
                    sums += __shfl_xor(sums, off, 16);
                    sumw += __shfl_xor(sumw, off, 16);
                }
                lsel[r] = lsel[r] * axs[r] + sums; msel[r] = msn;
                lswa[r] = lswa[r] * axw[r] + sumw; mswa[r] = mwn;

                const int prow = (quad * 4 + r) * kPSt;
                *(half2v*)&PS[prow + 2 * l15]      = (half2v){(_Float16)es[0], (_Float16)es[1]};
                *(half2v*)&PS[prow + 32 + 2 * l15] = (half2v){(_Float16)es[2], (_Float16)es[3]};
                *(half2v*)&PW[prow + 2 * l15]      = (half2v){(_Float16)ew[0], (_Float16)ew[1]};
                *(half2v*)&PW[prow + 32 + 2 * l15] = (half2v){(_Float16)ew[2], (_Float16)ew[3]};
            }
        } else if (bsel) {
            #pragma unroll
            for (int r = 0; r < 4; ++r) {
                float mxs = kNEG;
                #pragma unroll
                for (int kt = 0; kt < 4; ++kt)
                    if (ca[kt]) mxs = fmaxf(mxs, acc[kt][r]);
                #pragma unroll
                for (int off = 8; off; off >>= 1)
                    mxs = fmaxf(mxs, __shfl_xor(mxs, off, 16));
                const float msn = fmaxf(msel[r], mxs);
                axs[r] = __expf(msel[r] - msn);
                float es[4];
                #pragma unroll
                for (int kt = 0; kt < 4; ++kt)
                    es[kt] = ca[kt] ? __expf(acc[kt][r] - msn) : 0.f;
                float sums = (es[0] + es[1]) + (es[2] + es[3]);
                #pragma unroll
                for (int off = 8; off; off >>= 1)
                    sums += __shfl_xor(sums, off, 16);
                lsel[r] = lsel[r] * axs[r] + sums; msel[r] = msn;

                const int prow = (quad * 4 + r) * kPSt;
                *(half2v*)&PS[prow + 2 * l15]      = (half2v){(_Float16)es[0], (_Float16)es[1]};
                *(half2v*)&PS[prow + 32 + 2 * l15] = (half2v){(_Float16)es[2], (_Float16)es[3]};
            }
        } else {
            #pragma unroll
            for (int r = 0; r < 4; ++r) {
                float mxw = kNEG;
                #pragma unroll
                for (int kt = 0; kt < 4; ++kt)
                    if (wi[kt]) mxw = fmaxf(mxw, acc[kt][r]);
                #pragma unroll
                for (int off = 8; off; off >>= 1)
                    mxw = fmaxf(mxw, __shfl_xor(mxw, off, 16));
                const float mwn = fmaxf(mswa[r], mxw);
                axw[r] = __expf(mswa[r] - mwn);
                float ew[4];
                #pragma unroll
                for (int kt = 0; kt < 4; ++kt)
                    ew[kt] = wi[kt] ? __expf(acc[kt][r] - mwn) : 0.f;
                float sumw = (ew[0] + ew[1]) + (ew[2] + ew[3]);
                #pragma unroll
                for (int off = 8; off; off >>= 1)
                    sumw += __shfl_xor(sumw, off, 16);
                lswa[r] = lswa[r] * axw[r] + sumw; mswa[r] = mwn;

                const int prow = (quad * 4 + r) * kPSt;
                *(half2v*)&PW[prow + 2 * l15]      = (half2v){(_Float16)ew[0], (_Float16)ew[1]};
                *(half2v*)&PW[prow + 32 + 2 * l15] = (half2v){(_Float16)ew[2], (_Float16)ew[3]};
            }
        }

        // ---- PV: A-frags from per-wave P slab (in-wave lgkmcnt ordering,
        //          no barrier); V B-frags straight from vt (L2) ----
        half8 apS[2], apW[2];
        if (bsel) {
            apS[0] = *(const half8*)&PS[l15 * kPSt + quad * 8];
            apS[1] = *(const half8*)&PS[l15 * kPSt + 32 + quad * 8];
        }
        if (bswa) {
            apW[0] = *(const half8*)&PW[l15 * kPSt + quad * 8];
            apW[1] = *(const half8*)&PW[l15 * kPSt + 32 + quad * 8];
        }

        #pragma unroll
        for (int n8 = 0; n8 < 8; ++n8) {
            const _Float16* vp = vt + (size_t)(n8 * 16 + l15) * kVTCols + b * kBS + quad * 8;
            const half8 v0 = *(const half8*)(vp);
            const half8 v1 = *(const half8*)(vp + 32);
            if (bsel) {
                #pragma unroll
                for (int r = 0; r < 4; ++r) osel[n8][r] *= axs[r];
                osel[n8] = __builtin_amdgcn_mfma_f32_16x16x32_f16(apS[0], v0, osel[n8], 0, 0, 0);
                osel[n8] = __builtin_amdgcn_mfma_f32_16x16x32_f16(apS[1], v1, osel[n8], 0, 0, 0);
            }
            if (bswa) {
                #pragma unroll
                for (int r = 0; r < 4; ++r) oswa[n8][r] *= axw[r];
                oswa[n8] = __builtin_amdgcn_mfma_f32_16x16x32_f16(apW[0], v0, oswa[n8], 0, 0, 0);
                oswa[n8] = __builtin_amdgcn_mfma_f32_16x16x32_f16(apW[1], v1, oswa[n8], 0, 0, 0);
            }
        }
    }

    // ---- epilogue: normalizers + sigmoid combine (all in-register) ----
    float lsI[4], lwI[4];
    #pragma unroll
    for (int r = 0; r < 4; ++r) { lsI[r] = 1.f / lsel[r]; lwI[r] = 1.f / lswa[r]; }

    #pragma unroll
    for (int r = 0; r < 4; ++r) {
        const int h = quad * 4 + r;
        const float c1 = cw[((size_t)t_w * kHQ + h) * 3 + 1];
        const float c2 = cw[((size_t)t_w * kHQ + h) * 3 + 2];
        const float w1 = 1.f / (1.f + __expf(-c1));
        const float w2 = 1.f / (1.f + __expf(-c2));
        float* op = out + ((size_t)t_w * kHQ + h) * kD + l15;
        #pragma unroll
        for (int n8 = 0; n8 < 8; ++n8)
            op[n8 * 16] += w1 * osel[n8][r] * lsI[r] + w2 * oswa[n8][r] * lwI[r];
    }
}

// ---------------------------------------------------------------------
extern "C" void kernel_launch(void* const* d_in, const int* in_sizes, int n_in,
                              void* d_out, int out_size, void* d_ws, size_t ws_size,
                              hipStream_t stream) {
    const float* q  = (const float*)d_in[0];
    const float* k  = (const float*)d_in[1];
    const float* v  = (const float*)d_in[2];
    const float* cw = (const float*)d_in[3];
    float* out = (float*)d_out;

    float* ws = (float*)d_ws;
    float* cmp_k = ws;                                   // 128*128 fp32
    unsigned* sel_mask = (unsigned*)(cmp_k + 128 * kD);  // T u32
    short* kb      = (short*)(sel_mask + kT);            // kKBRows*kD bf16
    _Float16* vt   = (_Float16*)(kb + (size_t)kKBRows * kD);  // kD*kVTCols fp16
    short* cvt     = (short*)(vt + (size_t)kD * kVTCols);     // 128*128 bf16

    k_stage<<<dim3(kKBRows + 128), dim3(kD), 0, stream>>>(k, v, kb, vt, cmp_k, cvt);
    k_cmp_attn<<<dim3(kT), dim3(256), 0, stream>>>(q, cw, cmp_k, cvt, sel_mask, out);
    k_attn_tile<<<dim3(kT / kQT), dim3(256), 0, stream>>>(q, kb, vt, cw, sel_mask, out);
}

// Round 2
// 219.105 us; speedup vs baseline: 1.1851x; 1.1851x over previous
//
#include <hip/hip_runtime.h>
#include <math.h>

// ---- NSA hyperparameters (compile-time, matches reference config) ----
constexpr int kT    = 2048;
constexpr int kHQ   = 16;
constexpr int kD    = 128;
constexpr int kKS   = 32;
constexpr int kST   = 16;
constexpr int kBS   = 64;
constexpr int kM    = (kT - kKS) / kST + 1;   // 127 compressed tokens
constexpr int kNB   = (kT + kBS - 1) / kBS;   // 32 selection blocks
constexpr int kTopN = 16;
constexpr int kNInit = 2;
constexpr int kWIN  = 512;
constexpr float kNEG = -1e30f;
constexpr float kScale = 0.08838834764831845f; // 128^-0.5

constexpr int kPad    = 32;
constexpr int kKBRows = kT + kPad; // 2080
constexpr int kVTCols = kT + kPad; // 2080

// K2 (cmp-attn) LDS strides
constexpr int kQS2 = kD + 4;   // 132 floats
constexpr int kPS2 = 136;      // fp32 probs (136: head-group bank spread)
constexpr int kPB2 = 136;      // bf16 probs

// K4 tiled attention (kQT=4: 4 waves, 4 queries, grid=512)
constexpr int kQT   = 4;
constexpr int kPSt  = 72;         // P row stride (fp16)

typedef __attribute__((ext_vector_type(8))) short short8;
typedef __attribute__((ext_vector_type(8))) _Float16 half8;
typedef __attribute__((ext_vector_type(2))) _Float16 half2v;
typedef __attribute__((ext_vector_type(4))) float floatx4;

// RNE float -> bf16 bits
__device__ inline short f2bf(float x) {
    unsigned u = __float_as_uint(x);
    unsigned r = (u + 0x7fffu + ((u >> 16) & 1u)) >> 16;
    return (short)r;
}

// ---------------------------------------------------------------------
// K1: fused staging.  blocks [0,2080): bf16 K rows + fp16 V^T cols,
// V^T stored with per-64-block key permutation col = 2l + (kt&1) + 32(kt>>1)
// (key = 16kt + l) so K4's P-writes pack as b32 pairs.
// blocks [2080,2208): mean-pool cmp_k fp32 + cmp V^T bf16.  block=(128)
// ---------------------------------------------------------------------
__global__ void k_stage(const float* __restrict__ k, const float* __restrict__ v,
                        short* __restrict__ kb, _Float16* __restrict__ vt,
                        float* __restrict__ cmp_k, short* __restrict__ cvt) {
    const int bid = blockIdx.x;
    const int d = threadIdx.x;
    if (bid < kKBRows) {
        const int row = bid;
        const int blk = row >> 6, w = row & 63;
        const int kt = w >> 4, l = w & 15;
        const int col = blk * kBS + l * 2 + (kt & 1) + (kt >> 1) * 32;
        if (row < kT) {
            kb[row * kD + d] = f2bf(k[(size_t)row * kD + d]);
            vt[(size_t)d * kVTCols + col] = (_Float16)v[(size_t)row * kD + d];
        } else {
            kb[row * kD + d] = 0;
            vt[(size_t)d * kVTCols + col] = (_Float16)0.f;
        }
    } else {
        const int m = bid - kKBRows;        // 0..127 (127 = zero pad row)
        float sk = 0.f, sv = 0.f;
        if (m < kM) {
            const int base = m * kST;
            #pragma unroll
            for (int i = 0; i < kKS; ++i) {
                sk += k[(size_t)(base + i) * kD + d];
                sv += v[(size_t)(base + i) * kD + d];
            }
            sk *= (1.0f / kKS);
            sv *= (1.0f / kKS);
        }
        cmp_k[m * kD + d] = sk;
        cvt[d * 128 + m] = f2bf(sv);
    }
}

// ---------------------------------------------------------------------
// K2: compressed attention + fused top-k, all 16 heads of one t.
// QK fp32 VALU; softmax wave-parallel (16-lane group per head, fp32,
// shfl reductions); slc_p+topk fused into lanes 0..31 with shfl argmax
// (lowest-index tie-break == serial scan semantics).  PV: bf16 MFMA.
// grid=(T), block=(256)
// ---------------------------------------------------------------------
__global__ __launch_bounds__(256) void k_cmp_attn(
        const float* __restrict__ q, const float* __restrict__ cw,
        const float* __restrict__ cmp_k, const short* __restrict__ cvt,
        unsigned* __restrict__ sel_mask, float* __restrict__ out) {
    const int t = blockIdx.x;
    const int tid = threadIdx.x;
    const int wave = tid >> 6;
    const int lane = tid & 63;
    const int l15 = lane & 15;
    const int quad = lane >> 4;

    __shared__ float q_s[kHQ * kQS2];
    __shared__ float p_s[kHQ * kPS2];
    __shared__ short Pb[kHQ * kPB2];

    // vectorized q staging: 512 float4s, 2 per thread
    for (int i = tid; i < kHQ * kD / 4; i += 256) {
        const int h = i >> 5, d4 = i & 31;
        *(float4*)&q_s[h * kQS2 + d4 * 4] = *(const float4*)&q[(size_t)t * kHQ * kD + i * 4];
    }
    __syncthreads();

    const int nvalid = (t >= kKS - 1) ? min(kM, (t - (kKS - 1)) / kST + 1) : 0;

    for (int idx = tid; idx < nvalid * 4; idx += 256) {
        const int m = idx >> 2;
        const int h0 = (idx & 3) * 4;
        const float4* k4 = (const float4*)(cmp_k + (size_t)m * kD);
        float a0 = 0.f, a1 = 0.f, a2 = 0.f, a3 = 0.f;
        #pragma unroll
        for (int i = 0; i < kD / 4; ++i) {
            const float4 b = k4[i];
            const float4 qa = *(const float4*)&q_s[(h0 + 0) * kQS2 + i * 4];
            const float4 qb = *(const float4*)&q_s[(h0 + 1) * kQS2 + i * 4];
            const float4 qc = *(const float4*)&q_s[(h0 + 2) * kQS2 + i * 4];
            const float4 qd = *(const float4*)&q_s[(h0 + 3) * kQS2 + i * 4];
            a0 = fmaf(qa.x, b.x, fmaf(qa.y, b.y, fmaf(qa.z, b.z, fmaf(qa.w, b.w, a0))));
            a1 = fmaf(qb.x, b.x, fmaf(qb.y, b.y, fmaf(qb.z, b.z, fmaf(qb.w, b.w, a1))));
            a2 = fmaf(qc.x, b.x, fmaf(qc.y, b.y, fmaf(qc.z, b.z, fmaf(qc.w, b.w, a2))));
            a3 = fmaf(qd.x, b.x, fmaf(qd.y, b.y, fmaf(qd.z, b.z, fmaf(qd.w, b.w, a3))));
        }
        p_s[(h0 + 0) * kPS2 + m] = a0 * kScale;
        p_s[(h0 + 1) * kPS2 + m] = a1 * kScale;
        p_s[(h0 + 2) * kPS2 + m] = a2 * kScale;
        p_s[(h0 + 3) * kPS2 + m] = a3 * kScale;
    }
    __syncthreads();

    // ---- wave-parallel softmax: 16-lane group per head, fp32 ----
    {
        const int h = tid >> 4;          // head 0..15
        const int j = tid & 15;
        float* p = p_s + h * kPS2;
        short* pb = Pb + h * kPB2;
        float loc[8];
        float mx = kNEG;
        #pragma unroll
        for (int i = 0; i < 8; ++i) {
            const int m = j + i * 16;
            const float val = (m < nvalid) ? p[m] : kNEG;
            loc[i] = val;
            mx = fmaxf(mx, val);
        }
        #pragma unroll
        for (int off = 8; off; off >>= 1) mx = fmaxf(mx, __shfl_xor(mx, off, 16));
        float e[8];
        float s = 0.f;
        #pragma unroll
        for (int i = 0; i < 8; ++i) {
            const int m = j + i * 16;
            const float ev = (m < nvalid) ? __expf(loc[i] - mx) : 0.f;
            e[i] = ev;
            s += ev;
        }
        #pragma unroll
        for (int off = 8; off; off >>= 1) s += __shfl_xor(s, off, 16);
        const float inv = (nvalid > 0) ? (1.f / s) : 0.f;
        #pragma unroll
        for (int i = 0; i < 8; ++i) {
            const int m = j + i * 16;
            const float pn = e[i] * inv;
            p[m] = pn;                 // zero-fills m >= nvalid too
            pb[m] = f2bf(pn);
        }
    }
    __syncthreads();

    // ---- fused slc_p + top-k: lanes 0..31 of wave 0 ----
    if (tid < kNB) {
        const int b = tid;
        const int m0 = 4 * b;
        float acc = 0.f;
        for (int h = 0; h < kHQ; ++h) {
            const float* p = p_s + h * kPS2;
            float a = 0.f;
            a += p[m0];
            a += p[m0 + 1];
            a += p[m0 + 2];
            a += 0.5f * p[m0 + 3];
            if (m0 - 1 >= 0) a += 0.5f * p[m0 - 1];
            acc += a;
        }
        const int cur = t / kBS;
        float x = acc;
        if (b > cur) x = kNEG;
        if (b < kNInit || b == cur) x = 1e30f;
        // 16 rounds of width-32 argmax; tie -> lowest index (serial semantics)
        bool taken = false;
        unsigned mask = 0;
        for (int n = 0; n < kTopN; ++n) {
            float v = taken ? -3.0e38f : x;
            int idx = b;
            #pragma unroll
            for (int off = 16; off; off >>= 1) {
                const float ov = __shfl_xor(v, off, 32);
                const int oi = __shfl_xor(idx, off, 32);
                if (ov > v || (ov == v && oi < idx)) { v = ov; idx = oi; }
            }
            mask |= 1u << idx;
            if (b == idx) taken = true;
        }
        if (tid == 0) sel_mask[t] = mask;
    }

    // ---- PV: bf16 MFMA (no barrier needed: Pb ready since last barrier) ----
    const int dimbase = wave * 32;
    floatx4 o[2] = {{0,0,0,0},{0,0,0,0}};
    #pragma unroll
    for (int kc = 0; kc < 4; ++kc) {
        const short8 ap = *(const short8*)&Pb[l15 * kPB2 + kc * 32 + quad * 8];
        #pragma unroll
        for (int nt = 0; nt < 2; ++nt) {
            const short8 b = *(const short8*)(cvt + (size_t)(dimbase + nt * 16 + l15) * 128 + kc * 32 + quad * 8);
            o[nt] = __builtin_amdgcn_mfma_f32_16x16x32_bf16(ap, b, o[nt], 0, 0, 0);
        }
    }

    #pragma unroll
    for (int r = 0; r < 4; ++r) {
        const int head = quad * 4 + r;
        const float c0 = cw[((size_t)t * kHQ + head) * 3 + 0];
        const float w0 = 1.f / (1.f + __expf(-c0));
        #pragma unroll
        for (int nt = 0; nt < 2; ++nt)
            out[((size_t)t * kHQ + head) * kD + dimbase + nt * 16 + l15] = w0 * o[nt][r];
    }
}

// ---------------------------------------------------------------------
// K4: barrier-free select+SWA attention.  One WAVE = one query t, all
// 128 output dims; 4 waves per block (grid=512), no inter-wave sync.
// Per active block (bitmask walk):
//   - issue ALL K-frag + V-frag global loads up front (regs, L2-hit);
//     softmax VALU work covers the V latency, QK covers nothing but
//     the K wait overlaps the 32-load issue burst + other waves
//   - QK bf16 MFMA -> per-head online softmax (per-path skip)
//   - P through per-wave-private LDS slab (in-wave lgkmcnt only)
//   - PV f16 MFMA from prefetched V regs
// blockIdx remap pairs light tile c with heavy tile 511-c on one CU.
// ---------------------------------------------------------------------
__global__ __launch_bounds__(256, 2) void k_attn_tile(
        const float* __restrict__ q, const short* __restrict__ kb,
        const _Float16* __restrict__ vt, const float* __restrict__ cw,
        const unsigned* __restrict__ sel_mask, float* __restrict__ out) {
    const int tid = threadIdx.x;
    const int wave = tid >> 6;
    const int lane = tid & 63;
    const int l15 = lane & 15;
    const int quad = lane >> 4;
    const int bid = blockIdx.x;
    const int tile = (bid < 256) ? bid : (767 - bid);   // light+heavy pairing per CU
    const int t_w = tile * kQT + wave;

    // per-wave private P slabs: [wave][path][16 rows x kPSt fp16]
    __shared__ _Float16 Pw[kQT][2][16 * kPSt];   // 18.4 KB total
    _Float16* const PS = &Pw[wave][0][0];
    _Float16* const PW = &Pw[wave][1][0];

    // A-fragments: q[t_w][head=l15][.] * kScale -> bf16
    short8 aq[4];
    {
        const float* qp = q + ((size_t)t_w * kHQ + l15) * kD + quad * 8;
        #pragma unroll
        for (int c = 0; c < 4; ++c) {
            const float4 f0 = *(const float4*)(qp + c * 32);
            const float4 f1 = *(const float4*)(qp + c * 32 + 4);
            short8 a;
            a[0] = f2bf(f0.x * kScale); a[1] = f2bf(f0.y * kScale);
            a[2] = f2bf(f0.z * kScale); a[3] = f2bf(f0.w * kScale);
            a[4] = f2bf(f1.x * kScale); a[5] = f2bf(f1.y * kScale);
            a[6] = f2bf(f1.z * kScale); a[7] = f2bf(f1.w * kScale);
            aq[c] = a;
        }
    }

    const unsigned selm = sel_mask[t_w];
    const int cur = t_w >> 6;
    const int lob = max(0, (t_w - (kWIN - 1)) >> 6);   // lowest block with any windowed key
    const unsigned lm = 0xFFFFFFFFu >> (31 - cur);     // bits 0..cur
    unsigned act = (selm & lm) | (lm & ~((1u << lob) - 1u));

    float msel[4], lsel[4], mswa[4], lswa[4];
    #pragma unroll
    for (int r = 0; r < 4; ++r) { msel[r] = kNEG; lsel[r] = 0.f; mswa[r] = kNEG; lswa[r] = 0.f; }
    floatx4 osel[8], oswa[8];
    #pragma unroll
    for (int n8 = 0; n8 < 8; ++n8) {
        osel[n8] = (floatx4){0,0,0,0};
        oswa[n8] = (floatx4){0,0,0,0};
    }

    while (act) {
        const int b = __builtin_ctz(act);
        act &= act - 1u;
        const bool bsel = (selm >> b) & 1u;
        const bool bswa = b >= lob;

        // ---- issue all K loads, then all V loads (regs; L2-resident) ----
        short8 kreg[4][4];
        {
            const short* kp = kb + (size_t)(b * kBS + l15) * kD + quad * 8;
            #pragma unroll
            for (int kt = 0; kt < 4; ++kt)
                #pragma unroll
                for (int c = 0; c < 4; ++c)
                    kreg[kt][c] = *(const short8*)(kp + kt * 16 * kD + c * 32);
        }
        half8 vreg[8][2];
        {
            const _Float16* vp = vt + (size_t)l15 * kVTCols + b * kBS + quad * 8;
            #pragma unroll
            for (int n8 = 0; n8 < 8; ++n8) {
                vreg[n8][0] = *(const half8*)(vp + (size_t)(n8 * 16) * kVTCols);
                vreg[n8][1] = *(const half8*)(vp + (size_t)(n8 * 16) * kVTCols + 32);
            }
        }

        // ---- QK ----
        floatx4 acc[4];
        #pragma unroll
        for (int kt = 0; kt < 4; ++kt) {
            acc[kt] = (floatx4){0,0,0,0};
            #pragma unroll
            for (int c = 0; c < 4; ++c)
                acc[kt] = __builtin_amdgcn_mfma_f32_16x16x32_bf16(aq[c], kreg[kt][c], acc[kt], 0, 0, 0);
        }

        bool ca[4], wi[4];
        #pragma unroll
        for (int kt = 0; kt < 4; ++kt) {
            const int key = b * kBS + kt * 16 + l15;
            ca[kt] = key <= t_w;
            wi[kt] = ca[kt] && (t_w - key) < kWIN;
        }

        // ---- online softmax (per-path, shared-exp when both active) ----
        float axs[4], axw[4];
        if (bsel && bswa) {
            #pragma unroll
            for (int r = 0; r < 4; ++r) {
                float mxs = kNEG, mxw = kNEG;
                #pragma unroll
                for (int kt = 0; kt < 4; ++kt) {
                    const float s = acc[kt][r];
                    if (ca[kt]) mxs = fmaxf(mxs, s);
                    if (wi[kt]) mxw = fmaxf(mxw, s);
                }
                #pragma unroll
                for (int off = 8; off; off >>= 1) {
                    mxs = fmaxf(mxs, __shfl_xor(mxs, off, 16));
                    mxw = fmaxf(mxw, __shfl_xor(mxw, off, 16));
                }
                const float msn = fmaxf(msel[r], mxs);
                const float mwn = fmaxf(mswa[r], mxw);
                axs[r] = __expf(msel[r] - msn);
                axw[r] = __expf(mswa[r] - mwn);
                const float cr = __expf(msn - mwn);
                float es[4], ew[4];
                #pragma unroll
                for (int kt = 0; kt < 4; ++kt) {
                    const float e0 = ca[kt] ? __expf(acc[kt][r] - msn) : 0.f;
                    es[kt] = e0;
                    ew[kt] = wi[kt] ? e0 * cr : 0.f;
                }
                float sums = (es[0] + es[1]) + (es[2] + es[3]);
                float sumw = (ew[0] + ew[1]) + (ew[2] + ew[3]);
                #pragma unroll
                for (int off = 8; off; off >>= 1) {
                    sums += __shfl_xor(sums, off, 16);
                    sumw += __shfl_xor(sumw, off, 16);
                }
                lsel[r] = lsel[r] * axs[r] + sums; msel[r] = msn;
                lswa[r] = lswa[r] * axw[r] + sumw; mswa[r] = mwn;

                const int prow = (quad * 4 + r) * kPSt;
                *(half2v*)&PS[prow + 2 * l15]      = (half2v){(_Float16)es[0], (_Float16)es[1]};
                *(half2v*)&PS[prow + 32 + 2 * l15] = (half2v){(_Float16)es[2], (_Float16)es[3]};
                *(half2v*)&PW[prow + 2 * l15]      = (half2v){(_Float16)ew[0], (_Float16)ew[1]};
                *(half2v*)&PW[prow + 32 + 2 * l15] = (half2v){(_Float16)ew[2], (_Float16)ew[3]};
            }
        } else if (bsel) {
            #pragma unroll
            for (int r = 0; r < 4; ++r) {
                float mxs = kNEG;
                #pragma unroll
                for (int kt = 0; kt < 4; ++kt)
                    if (ca[kt]) mxs = fmaxf(mxs, acc[kt][r]);
                #pragma unroll
                for (int off = 8; off; off >>= 1)
                    mxs = fmaxf(mxs, __shfl_xor(mxs, off, 16));
                const float msn = fmaxf(msel[r], mxs);
                axs[r] = __expf(msel[r] - msn);
                float es[4];
                #pragma unroll
                for (int kt = 0; kt < 4; ++kt)
                    es[kt] = ca[kt] ? __expf(acc[kt][r] - msn) : 0.f;
                float sums = (es[0] + es[1]) + (es[2] + es[3]);
                #pragma unroll
                for (int off = 8; off; off >>= 1)
                    sums += __shfl_xor(sums, off, 16);
                lsel[r] = lsel[r] * axs[r] + sums; msel[r] = msn;

                const int prow = (quad * 4 + r) * kPSt;
                *(half2v*)&PS[prow + 2 * l15]      = (half2v){(_Float16)es[0], (_Float16)es[1]};
                *(half2v*)&PS[prow + 32 + 2 * l15] = (half2v){(_Float16)es[2], (_Float16)es[3]};
            }
        } else {
            #pragma unroll
            for (int r = 0; r < 4; ++r) {
                float mxw = kNEG;
                #pragma unroll
                for (int kt = 0; kt < 4; ++kt)
                    if (wi[kt]) mxw = fmaxf(mxw, acc[kt][r]);
                #pragma unroll
                for (int off = 8; off; off >>= 1)
                    mxw = fmaxf(mxw, __shfl_xor(mxw, off, 16));
                const float mwn = fmaxf(mswa[r], mxw);
                axw[r] = __expf(mswa[r] - mwn);
                float ew[4];
                #pragma unroll
                for (int kt = 0; kt < 4; ++kt)
                    ew[kt] = wi[kt] ? __expf(acc[kt][r] - mwn) : 0.f;
                float sumw = (ew[0] + ew[1]) + (ew[2] + ew[3]);
                #pragma unroll
                for (int off = 8; off; off >>= 1)
                    sumw += __shfl_xor(sumw, off, 16);
                lswa[r] = lswa[r] * axw[r] + sumw; mswa[r] = mwn;

                const int prow = (quad * 4 + r) * kPSt;
                *(half2v*)&PW[prow + 2 * l15]      = (half2v){(_Float16)ew[0], (_Float16)ew[1]};
                *(half2v*)&PW[prow + 32 + 2 * l15] = (half2v){(_Float16)ew[2], (_Float16)ew[3]};
            }
        }

        // ---- PV: A-frags from per-wave P slab (in-wave lgkmcnt ordering);
        //          V B-frags already in registers ----
        half8 apS[2], apW[2];
        if (bsel) {
            apS[0] = *(const half8*)&PS[l15 * kPSt + quad * 8];
            apS[1] = *(const half8*)&PS[l15 * kPSt + 32 + quad * 8];
        }
        if (bswa) {
            apW[0] = *(const half8*)&PW[l15 * kPSt + quad * 8];
            apW[1] = *(const half8*)&PW[l15 * kPSt + 32 + quad * 8];
        }

        #pragma unroll
        for (int n8 = 0; n8 < 8; ++n8) {
            if (bsel) {
                #pragma unroll
                for (int r = 0; r < 4; ++r) osel[n8][r] *= axs[r];
                osel[n8] = __builtin_amdgcn_mfma_f32_16x16x32_f16(apS[0], vreg[n8][0], osel[n8], 0, 0, 0);
                osel[n8] = __builtin_amdgcn_mfma_f32_16x16x32_f16(apS[1], vreg[n8][1], osel[n8], 0, 0, 0);
            }
            if (bswa) {
                #pragma unroll
                for (int r = 0; r < 4; ++r) oswa[n8][r] *= axw[r];
                oswa[n8] = __builtin_amdgcn_mfma_f32_16x16x32_f16(apW[0], vreg[n8][0], oswa[n8], 0, 0, 0);
                oswa[n8] = __builtin_amdgcn_mfma_f32_16x16x32_f16(apW[1], vreg[n8][1], oswa[n8], 0, 0, 0);
            }
        }
    }

    // ---- epilogue: normalizers + sigmoid combine (all in-register) ----
    float lsI[4], lwI[4];
    #pragma unroll
    for (int r = 0; r < 4; ++r) { lsI[r] = 1.f / lsel[r]; lwI[r] = 1.f / lswa[r]; }

    #pragma unroll
    for (int r = 0; r < 4; ++r) {
        const int h = quad * 4 + r;
        const float c1 = cw[((size_t)t_w * kHQ + h) * 3 + 1];
        const float c2 = cw[((size_t)t_w * kHQ + h) * 3 + 2];
        const float w1 = 1.f / (1.f + __expf(-c1));
        const float w2 = 1.f / (1.f + __expf(-c2));
        float* op = out + ((size_t)t_w * kHQ + h) * kD + l15;
        #pragma unroll
        for (int n8 = 0; n8 < 8; ++n8)
            op[n8 * 16] += w1 * osel[n8][r] * lsI[r] + w2 * oswa[n8][r] * lwI[r];
    }
}

// ---------------------------------------------------------------------
extern "C" void kernel_launch(void* const* d_in, const int* in_sizes, int n_in,
                              void* d_out, int out_size, void* d_ws, size_t ws_size,
                              hipStream_t stream) {
    const float* q  = (const float*)d_in[0];
    const float* k  = (const float*)d_in[1];
    const float* v  = (const float*)d_in[2];
    const float* cw = (const float*)d_in[3];
    float* out = (float*)d_out;

    float* ws = (float*)d_ws;
    float* cmp_k = ws;                                   // 128*128 fp32
    unsigned* sel_mask = (unsigned*)(cmp_k + 128 * kD);  // T u32
    short* kb      = (short*)(sel_mask + kT);            // kKBRows*kD bf16
    _Float16* vt   = (_Float16*)(kb + (size_t)kKBRows * kD);  // kD*kVTCols fp16
    short* cvt     = (short*)(vt + (size_t)kD * kVTCols);     // 128*128 bf16

    k_stage<<<dim3(kKBRows + 128), dim3(kD), 0, stream>>>(k, v, kb, vt, cmp_k, cvt);
    k_cmp_attn<<<dim3(kT), dim3(256), 0, stream>>>(q, cw, cmp_k, cvt, sel_mask, out);
    k_attn_tile<<<dim3(kT / kQT), dim3(256), 0, stream>>>(q, kb, vt, cw, sel_mask, out);
}